// Round 9
// baseline (954.029 us; speedup 1.0000x reference)
//
#include <hip/hip_runtime.h>

typedef unsigned int  u32;
typedef unsigned short u16;
typedef float  f32x4 __attribute__((ext_vector_type(4)));
typedef u32    u32x4 __attribute__((ext_vector_type(4)));
typedef __bf16 bf16x8 __attribute__((ext_vector_type(8)));
typedef _Float16 f16;
typedef _Float16 f16x8 __attribute__((ext_vector_type(8)));
typedef _Float16 f16x2 __attribute__((ext_vector_type(2)));

static constexpr int NPED = 4096;
static constexpr int H = 64, E = 16, BOT = 32, PPH = 512;
static constexpr int TSTEPS = 12;

// ---------- helpers ----------
__device__ __forceinline__ float bf2f(u16 u) {
  return __builtin_bit_cast(float, ((u32)u) << 16);
}
__device__ __forceinline__ u16 f2bf(float f) {  // RNE
  u32 u = __builtin_bit_cast(u32, f);
  u += 0x7fffu + ((u >> 16) & 1u);
  return (u16)(u >> 16);
}
__device__ __forceinline__ u16 f2h(float f) {   // f32 -> f16 bits (RNE)
  return __builtin_bit_cast(u16, (f16)f);
}
__device__ __forceinline__ float sigm(float x) { return 1.f / (1.f + __expf(-x)); }
__device__ __forceinline__ float tanhf_(float x) {
  float t = fabsf(x);
  float e = __expf(-2.f * t);
  float r = (1.f - e) / (1.f + e);
  return x < 0.f ? -r : r;
}
__device__ __forceinline__ f16x8 relu8(f16x8 t) {
  const f16x8 z = {(f16)0, (f16)0, (f16)0, (f16)0, (f16)0, (f16)0, (f16)0, (f16)0};
#if __has_builtin(__builtin_elementwise_max)
  return __builtin_elementwise_max(t, z);
#else
  #pragma unroll
  for (int q = 0; q < 8; ++q) t[q] = t[q] > (f16)0 ? t[q] : (f16)0;
  return t;
#endif
}

// async 16B global->LDS copy (wave-uniform LDS base + lane*16 layout).
__device__ __forceinline__ void gload_lds16(const u16* __restrict__ g, u16* l) {
#if __has_builtin(__builtin_amdgcn_global_load_lds)
  __builtin_amdgcn_global_load_lds(
      (const __attribute__((address_space(1))) void*)g,
      (__attribute__((address_space(3))) void*)l, 16, 0, 0);
#else
  *(u32x4*)l = *(const u32x4*)g;
#endif
}

// ---------- workspace layout (bytes) ----------
static constexpr size_t OFF_C    = 0;        // f32 [4096][64]
static constexpr size_t OFF_HL   = 1048576;  // f32 [4096][64]
static constexpr size_t OFF_POS  = 2097152;  // f32 [4096][2]
static constexpr size_t OFF_X    = 2129920;  // f32 [4096][16]
static constexpr size_t OFF_POOL = 2392064;  // f32 [4096][32]
static constexpr size_t OFF_ABF  = 2916352;  // f16 [4096][512]  (buffer 0)
static constexpr size_t OFF_A3   = 7110656;  // f32 [3][512]
static constexpr size_t OFF_CST  = 7116800;  // f32 [512]
static constexpr size_t OFF_W2T  = 7118848;  // f16 [32][512]
// packed B-fragment weights (lane-ordered, bf16 hi + bf16 lo residual)
static constexpr size_t OFF_GWH  = 7151616;  // gates  [16 t][3 ks][64 lane][8]
static constexpr size_t OFF_GWL  = 7200768;
static constexpr size_t OFF_D1H  = 7249920;  // dec1   [4][3][64][8]
static constexpr size_t OFF_D1L  = 7262208;
static constexpr size_t OFF_D2H  = 7274496;  // dec2   [4][2][64][8]
static constexpr size_t OFF_D2L  = 7282688;
static constexpr size_t OFF_PWH  = 7290880;  // a-prep [32][2][64][8]
static constexpr size_t OFF_PWL  = 7356416;
static constexpr size_t OFF_ABF2 = 7421952;  // f16 [4096][512]  (buffer 1)
static constexpr size_t ABF_BYTES = (size_t)NPED * PPH * 2;   // 4 MiB
static constexpr size_t WS_NEED_FUSED = OFF_ABF2 + ABF_BYTES; // ~11.1 MiB
static constexpr size_t WS_NEED_PERS  = OFF_ABF + ABF_BYTES;  // persistent: 1 a-buffer

// fallback pool smem: a_s(f16) + w2_s(f16) + v_s(f16) + red(f32)
static constexpr int POOL_SMEM = 64*520*2 + 32*520*2 + 16*512*2 + 16*4*2*16*4; // 124416
// R8 fused smem
static constexpr int FUSED_SMEM = POOL_SMEM + 64 + 128 + 128;  // 124736
// persistent per-scene kernel:
//   pool phase:  a_s[64][520]u16 + w2_s[32][520]u16 + v_s[16][512]f16 + red 8K = 124416
//   step phase:  zin[64][100] + o1[64][68] + as_[64][100] + hl[64][68] + gl[64][260] (f32) = 152576
//   persistent tail: pool_out[64][32]f32 + spd[64] + rel[64][2] + pos[64][2]
static constexpr int PERS_UNION = 152576;
static constexpr int PERS_SMEM  = PERS_UNION + 64*32*4 + 64*4 + 64*2*4 + 64*2*4; // 162048

// ---------- setup: state init + folded constants + fragment packing ----------
__global__ void k_setup(const float* __restrict__ last_pos, const float* __restrict__ last_pos_rel,
                        const float* __restrict__ c0, const float* __restrict__ pps,
                        const float* __restrict__ W_sp, const float* __restrict__ b_sp,
                        const float* __restrict__ W_pe, const float* __restrict__ b_pe,
                        const float* __restrict__ W_pp1, const float* __restrict__ b_pp1,
                        const float* __restrict__ W_pp2,
                        const float* __restrict__ W_ih, const float* __restrict__ W_hh,
                        const float* __restrict__ W_m1, const float* __restrict__ W_m2,
                        float* __restrict__ c, float* __restrict__ pos, float* __restrict__ x,
                        float* __restrict__ A3, float* __restrict__ Cst, u16* __restrict__ W2t,
                        u16* GWH, u16* GWL, u16* D1H, u16* D1L,
                        u16* D2H, u16* D2L, u16* PWH, u16* PWL)
{
  const int stride = gridDim.x * blockDim.x;
  const int tid0 = blockIdx.x * blockDim.x + threadIdx.x;
  for (int i = tid0; i < NPED * H; i += stride) c[i] = c0[i];
  for (int i = tid0; i < NPED * 2; i += stride) pos[i] = last_pos[i];
  for (int i = tid0; i < NPED * E; i += stride) {
    int n = i >> 4, e = i & 15;
    x[i] = last_pos_rel[2*n] * W_sp[e] + last_pos_rel[2*n+1] * W_sp[16+e]
         + pps[n] * W_sp[32+e] + b_sp[e];
  }
  for (int i = tid0; i < 3 * PPH; i += stride) {   // A3 = W_pe @ W_pp1[64:80]
    int r = i >> 9, k = i & 511;
    float s = 0.f;
    for (int e = 0; e < 16; ++e) s += W_pe[r*16+e] * W_pp1[(64+e)*PPH + k];
    A3[i] = s;
  }
  for (int i = tid0; i < PPH; i += stride) {       // Cst = b_pe @ W_pp1[64:80] + b_pp1
    float s = b_pp1[i];
    for (int e = 0; e < 16; ++e) s += b_pe[e] * W_pp1[(64+e)*PPH + i];
    Cst[i] = s;
  }
  for (int i = tid0; i < 32 * PPH; i += stride) {  // W2t[n][k] = f16(W_pp2[k][n])
    int n = i >> 9, k = i & 511;
    W2t[i] = f2h(W_pp2[k*32 + n]);
  }
  // gates pack: [K=96 pad][N=256], A = [x(16)|h(64)|0(16)]
  for (int i = tid0; i < 256*96; i += stride) {
    int n = i / 96, k = i - n*96;
    float wv = (k < 16) ? W_ih[k*256+n] : ((k < 80) ? W_hh[(k-16)*256+n] : 0.f);
    u16 hi = f2bf(wv); u16 lo = f2bf(wv - bf2f(hi));
    int idx = (((n>>4)*3 + (k>>5))*64 + ((k>>3)&3)*16 + (n&15))*8 + (k&7);
    GWH[idx] = hi; GWL[idx] = lo;
  }
  // dec1 pack: W_m1 [96][64]
  for (int i = tid0; i < 64*96; i += stride) {
    int n = i / 96, k = i - n*96;
    float wv = W_m1[k*64 + n];
    u16 hi = f2bf(wv); u16 lo = f2bf(wv - bf2f(hi));
    int idx = (((n>>4)*3 + (k>>5))*64 + ((k>>3)&3)*16 + (n&15))*8 + (k&7);
    D1H[idx] = hi; D1L[idx] = lo;
  }
  // dec2 pack: W_m2 [64][64]
  for (int i = tid0; i < 64*64; i += stride) {
    int n = i >> 6, k = i & 63;
    float wv = W_m2[k*64 + n];
    u16 hi = f2bf(wv); u16 lo = f2bf(wv - bf2f(hi));
    int idx = (((n>>4)*2 + (k>>5))*64 + ((k>>3)&3)*16 + (n&15))*8 + (k&7);
    D2H[idx] = hi; D2L[idx] = lo;
  }
  // a-prep pack: W_pp1[:64] [64][512]
  for (int i = tid0; i < 512*64; i += stride) {
    int n = i >> 6, k = i & 63;
    float wv = W_pp1[k*PPH + n];
    u16 hi = f2bf(wv); u16 lo = f2bf(wv - bf2f(hi));
    int idx = (((n>>4)*2 + (k>>5))*64 + ((k>>3)&3)*16 + (n&15))*8 + (k&7);
    PWH[idx] = hi; PWL[idx] = lo;
  }
}

// ---------- split MFMA helpers ----------
template<int NT, int NKS>
__device__ __forceinline__ void load_frags(const u16* __restrict__ WH, const u16* __restrict__ WL,
                                           int tile0, int lane,
                                           u32x4 (&bh)[NT][NKS], u32x4 (&bl)[NT][NKS])
{
  #pragma unroll
  for (int i = 0; i < NT; ++i)
    #pragma unroll
    for (int ks = 0; ks < NKS; ++ks) {
      int o = (((tile0 + i)*NKS + ks)*64 + lane)*8;
      bh[i][ks] = *(const u32x4*)(WH + o);
      bl[i][ks] = *(const u32x4*)(WL + o);
    }
}

template<int NT, int NKS>
__device__ __forceinline__ void mfma_compute(const u32x4 (&bh)[NT][NKS], const u32x4 (&bl)[NT][NKS],
                                             int lane, const float* arow, f32x4* acc)
{
  const int kg = lane >> 4;
  #pragma unroll
  for (int ks = 0; ks < NKS; ++ks) {
    f32x4 a0 = *(const f32x4*)(arow + ks*32 + kg*8);
    f32x4 a1 = *(const f32x4*)(arow + ks*32 + kg*8 + 4);
    float av[8] = {a0.x,a0.y,a0.z,a0.w,a1.x,a1.y,a1.z,a1.w};
    bf16x8 ah, al;
    #pragma unroll
    for (int j = 0; j < 8; ++j) {
      __bf16 hbits = (__bf16)av[j];
      ah[j] = hbits;
      al[j] = (__bf16)(av[j] - (float)hbits);
    }
    #pragma unroll
    for (int i = 0; i < NT; ++i) {
      bf16x8 BH = __builtin_bit_cast(bf16x8, bh[i][ks]);
      bf16x8 BL = __builtin_bit_cast(bf16x8, bl[i][ks]);
      acc[i] = __builtin_amdgcn_mfma_f32_16x16x32_bf16(ah, BH, acc[i], 0, 0, 0);
      acc[i] = __builtin_amdgcn_mfma_f32_16x16x32_bf16(ah, BL, acc[i], 0, 0, 0);
      acc[i] = __builtin_amdgcn_mfma_f32_16x16x32_bf16(al, BH, acc[i], 0, 0, 0);
    }
  }
}

template<int NT, int NKS>
__device__ __forceinline__ void mfma_block(
    const u16* __restrict__ WH, const u16* __restrict__ WL, int tile0, int lane,
    const float* arow, int acol0, f32x4* acc)
{
  u32x4 bh[NT][NKS], bl[NT][NKS];
  load_frags<NT,NKS>(WH, WL, tile0, lane, bh, bl);
  mfma_compute<NT,NKS>(bh, bl, lane, arow + acol0, acc);
}

// ---------- persistent per-scene kernel: all 12 steps, zero cross-block deps ----------
// grid = 64 blocks (1 scene each) x 1024 threads. State in registers/LDS.
// Only global traffic per step: own scene's a (write then read, same CU -> L1-coherent
// after __syncthreads vmcnt drain), weights (L1/L2-resident), pps, out.
__global__ __launch_bounds__(1024) void k_pers(
    const float* __restrict__ h0, const float* __restrict__ c0,
    const float* __restrict__ pps,
    const float* __restrict__ last_pos, const float* __restrict__ x_g,
    const float* __restrict__ b_ih, const float* __restrict__ b_hh,
    const float* __restrict__ W_h2p, const float* __restrict__ b_h2p,
    const float* __restrict__ W_sp, const float* __restrict__ b_sp,
    const float* __restrict__ b_m1, const float* __restrict__ b_m2,
    const float* __restrict__ A3, const float* __restrict__ Cst,
    const u16* __restrict__ GWH, const u16* __restrict__ GWL,
    const u16* __restrict__ D1H, const u16* __restrict__ D1L,
    const u16* __restrict__ D2H, const u16* __restrict__ D2L,
    const u16* __restrict__ PWH, const u16* __restrict__ PWL,
    const u16* __restrict__ W2t, const float* __restrict__ b_pp2,
    u16* __restrict__ a_g, float* __restrict__ out)
{
  constexpr int LDA = 520;
  extern __shared__ char smem[];
  // pool-phase view
  u16*   a_s  = (u16*)smem;                       // [64][520]
  u16*   w2_s = a_s + 64 * LDA;                   // [32][520]
  f16*   v_s  = (f16*)(w2_s + 32 * LDA);          // [16][512] (per i-group)
  float* red  = (float*)(v_s + 16 * 512);         // [16][4][2][16]
  // step-phase view (aliases pool region; phases strictly separated by barriers)
  float* zin = (float*)smem;                      // [64][100]
  float* o1  = zin + 64*100;                      // [64][68]
  float* as_ = o1  + 64*68;                       // [64][100]
  float* hl  = as_ + 64*100;                      // [64][68]
  float* gl  = hl  + 64*68;                       // [64][260] (ends 152576)
  // persistent tail
  float* pool_out = (float*)(smem + PERS_UNION);  // [64][32]
  float* spd_s    = pool_out + 64*32;             // [64]
  float* rel_s    = spd_s + 64;                   // [64][2]
  float* pos_s    = rel_s + 128;                  // [64][2]

  const int tid = threadIdx.x;
  const int base = blockIdx.x * 64;               // scene ped base
  const int lane = tid & 63, w = tid >> 6;
  const int colq = lane & 15, kg = lane >> 4;
  const int sd = lane;

  // ---- persistent state ----
  float creg[4], hreg[4];
  #pragma unroll
  for (int q = 0; q < 4; ++q) {
    int p = w + 16*q;
    creg[q] = c0[(base + p)*H + sd];
    hreg[q] = h0[(base + p)*H + sd];
  }
  float xreg = x_g[(base + (tid >> 4))*E + (tid & 15)];
  const float whp0 = W_h2p[2*sd], whp1 = W_h2p[2*sd + 1];
  if (tid < 64) {
    pos_s[tid*2+0] = last_pos[(base + tid)*2+0];
    pos_s[tid*2+1] = last_pos[(base + tid)*2+1];
  }
  __syncthreads();

  for (int t = 0; t < TSTEPS; ++t) {
    const int tsp = (t + 1 < 12) ? t + 1 : 11;
    if (tid < 64) spd_s[tid] = pps[tsp * NPED + base + tid];

    if (t > 0) {
      // ---- stage a (own scene, written by this block last step) + w2 via DMA ----
      #pragma unroll
      for (int q = 0; q < 4; ++q) {
        int r = w + 16*q;
        gload_lds16(&a_g[(size_t)(base + r)*PPH + lane*8], &a_s[r*LDA + lane*8]);
      }
      #pragma unroll
      for (int q = 0; q < 2; ++q) {
        int r = w + 16*q;
        gload_lds16(&W2t[(size_t)r*PPH + lane*8], &w2_s[r*LDA + lane*8]);
      }

      // ---- pool: 4 groups of 16 i, verified inner loop per group ----
      const int jq = w & 3, g2 = w >> 2;
      const int aoff  = (jq*16 + colq)*LDA + kg*8;
      const int w0off = colq*LDA + kg*8;
      const int w1off = (colq + 16)*LDA + kg*8;
      const float b20 = b_pp2[colq];
      const float b21 = b_pp2[colq + 16];

      for (int gg = 0; gg < 4; ++gg) {
        // stage v for i in [gg*16, gg*16+16); reduce previous red meanwhile
        for (int idx = tid; idx < 4096; idx += 1024) {
          int il = idx >> 8, k2 = (idx & 255)*2;
          int i = gg*16 + il;
          float px = pos_s[i*2], py = pos_s[i*2+1];
          float v0 = px*A3[k2]     + py*A3[512 + k2];
          float v1 = px*A3[k2+1]   + py*A3[512 + k2 + 1];
          f16x2 pk = { (f16)v0, (f16)v1 };
          *(f16x2*)&v_s[il*512 + k2] = pk;
        }
        if (gg > 0 && tid < 512) {
          int g3 = tid >> 7, ii = (tid >> 5) & 3, tile = (tid >> 4) & 1, cc = tid & 15;
          float m = red[(((g3*4 + 0)*4 + ii)*2 + tile)*16 + cc];
          #pragma unroll
          for (int q = 1; q < 4; ++q)
            m = fmaxf(m, red[(((g3*4 + q)*4 + ii)*2 + tile)*16 + cc]);
          pool_out[((gg-1)*16 + g3*4 + ii)*32 + tile*16 + cc] = m;
        }
        __syncthreads();   // first iter: also drains a/w2 DMA

        f32x4 accA[4], accB[4];
        #pragma unroll
        for (int ii = 0; ii < 4; ++ii) {
          accA[ii] = (f32x4){0.f,0.f,0.f,0.f};
          accB[ii] = (f32x4){0.f,0.f,0.f,0.f};
        }
        for (int kk = 0; kk < 16; ++kk) {
          const int ke = kk * 32;
          f16x8 a8  = __builtin_bit_cast(f16x8, *(const u32x4*)&a_s[aoff + ke]);
          f16x8 bw0 = __builtin_bit_cast(f16x8, *(const u32x4*)&w2_s[w0off + ke]);
          f16x8 bw1 = __builtin_bit_cast(f16x8, *(const u32x4*)&w2_s[w1off + ke]);
          #pragma unroll
          for (int ii = 0; ii < 4; ++ii) {
            f16x8 v8 = *(const f16x8*)&v_s[(g2*4 + ii)*512 + ke + kg*8];
            f16x8 tq = relu8(a8 - v8);
            accA[ii] = __builtin_amdgcn_mfma_f32_16x16x32_f16(tq, bw0, accA[ii], 0, 0, 0);
            accB[ii] = __builtin_amdgcn_mfma_f32_16x16x32_f16(tq, bw1, accB[ii], 0, 0, 0);
          }
        }
        #pragma unroll
        for (int ii = 0; ii < 4; ++ii) {
          float m0 = 0.f, m1 = 0.f;
          #pragma unroll
          for (int r = 0; r < 4; ++r) {
            m0 = fmaxf(m0, accA[ii][r] + b20);
            m1 = fmaxf(m1, accB[ii][r] + b21);
          }
          m0 = fmaxf(m0, __shfl_xor(m0, 16, 64));
          m0 = fmaxf(m0, __shfl_xor(m0, 32, 64));
          m1 = fmaxf(m1, __shfl_xor(m1, 16, 64));
          m1 = fmaxf(m1, __shfl_xor(m1, 32, 64));
          if (kg == 0) {
            red[((w*4 + ii)*2 + 0)*16 + colq] = m0;
            red[((w*4 + ii)*2 + 1)*16 + colq] = m1;
          }
        }
        __syncthreads();
      }

      // ---- final reduce (gg=3) + step staging (a_s/w2_s now dead) ----
      #pragma unroll
      for (int q = 0; q < 4; ++q) zin[(w + 16*q)*100 + sd] = hreg[q];
      if (tid < 512) {
        int g3 = tid >> 7, ii = (tid >> 5) & 3, tile = (tid >> 4) & 1, cc = tid & 15;
        float m = red[(((g3*4 + 0)*4 + ii)*2 + tile)*16 + cc];
        #pragma unroll
        for (int q = 1; q < 4; ++q)
          m = fmaxf(m, red[(((g3*4 + q)*4 + ii)*2 + tile)*16 + cc]);
        pool_out[(48 + g3*4 + ii)*32 + tile*16 + cc] = m;
      }
      { int p = tid >> 4, e = tid & 15;
        as_[p*100 + e] = xreg; as_[p*100 + 80 + e] = 0.f; }
      __syncthreads();
      for (int idx = tid; idx < 2048; idx += 1024) {
        int i = idx >> 5, j = idx & 31;
        zin[i*100 + 64 + j] = pool_out[i*32 + j];
      }
      __syncthreads();

      // ---- dec1: 4 M-tiles x 4 N-tiles = 16 wave-pairs (all waves busy) ----
      {
        const int mt = w >> 2, nt = w & 3;
        f32x4 acc = {0.f, 0.f, 0.f, 0.f};
        u32x4 dh[1][3], dl[1][3];
        load_frags<1,3>(D1H, D1L, nt, lane, dh, dl);
        mfma_compute<1,3>(dh, dl, lane, &zin[(mt*16 + colq)*100], &acc);
        int n = nt*16 + colq;
        float bm = b_m1[n];
        #pragma unroll
        for (int r = 0; r < 4; ++r)
          o1[(mt*16 + kg*4 + r)*68 + n] = fmaxf(acc[r] + bm, 0.f);
      }
      __syncthreads();

      // ---- dec2 ----
      {
        const int mt = w >> 2, nt = w & 3;
        f32x4 acc = {0.f, 0.f, 0.f, 0.f};
        u32x4 dh[1][2], dl[1][2];
        load_frags<1,2>(D2H, D2L, nt, lane, dh, dl);
        mfma_compute<1,2>(dh, dl, lane, &o1[(mt*16 + colq)*68], &acc);
        int n = nt*16 + colq;
        float bm = b_m2[n];
        #pragma unroll
        for (int r = 0; r < 4; ++r)
          as_[(mt*16 + kg*4 + r)*100 + 16 + n] = fmaxf(acc[r] + bm, 0.f);
      }
      __syncthreads();
    } else {
      // ---- t == 0: no pool/decoder; A-panel straight from h0/x ----
      #pragma unroll
      for (int q = 0; q < 4; ++q) as_[(w + 16*q)*100 + 16 + sd] = hreg[q];
      { int p = tid >> 4, e = tid & 15;
        as_[p*100 + e] = xreg; as_[p*100 + 80 + e] = 0.f; }
      __syncthreads();
    }

    // ---- gates: wave w owns N-tile w; loop over 4 M-tiles ----
    {
      u32x4 gh[1][3], glo[1][3];
      load_frags<1,3>(GWH, GWL, w, lane, gh, glo);
      const int n = w*16 + colq;
      const float bb = b_ih[n] + b_hh[n];
      #pragma unroll
      for (int mt = 0; mt < 4; ++mt) {
        f32x4 acc = {0.f, 0.f, 0.f, 0.f};
        mfma_compute<1,3>(gh, glo, lane, &as_[(mt*16 + colq)*100], &acc);
        #pragma unroll
        for (int r = 0; r < 4; ++r)
          gl[(mt*16 + kg*4 + r)*260 + n] = acc[r] + bb;
      }
    }
    __syncthreads();

    // ---- LSTM (4 peds/thread-wave) + fused h2p (64-lane reduce per ped) ----
    {
      float hv4[4];
      #pragma unroll
      for (int q = 0; q < 4; ++q) {
        int p = w + 16*q;
        float gi = gl[p*260 + sd], gf = gl[p*260 + 64 + sd],
              gg = gl[p*260 + 128 + sd], go = gl[p*260 + 192 + sd];
        float cn = sigm(gf)*creg[q] + sigm(gi)*tanhf_(gg);
        float hv = sigm(go)*tanhf_(cn);
        creg[q] = cn; hreg[q] = hv; hv4[q] = hv;
        hl[p*68 + sd] = hv;
      }
      #pragma unroll
      for (int q = 0; q < 4; ++q) {
        float s0 = hv4[q]*whp0, s1 = hv4[q]*whp1;
        #pragma unroll
        for (int m = 1; m < 64; m <<= 1) {
          s0 += __shfl_xor(s0, m, 64);
          s1 += __shfl_xor(s1, m, 64);
        }
        if (sd == 0) {
          int p = w + 16*q;
          float r0 = s0 + b_h2p[0], r1 = s1 + b_h2p[1];
          float px = pos_s[p*2+0] + r0, py = pos_s[p*2+1] + r1;
          pos_s[p*2+0] = px; pos_s[p*2+1] = py;
          rel_s[p*2+0] = r0; rel_s[p*2+1] = r1;
          int n = base + p;
          out[(t*NPED + n)*2] = r0; out[(t*NPED + n)*2 + 1] = r1;
        }
      }
    }
    __syncthreads();

    if (t < 11) {
      { // x_new (register; 1024 threads = 64 ped x 16 e)
        int p = tid >> 4, e = tid & 15;
        xreg = rel_s[p*2+0]*W_sp[e] + rel_s[p*2+1]*W_sp[16+e]
             + spd_s[p]*W_sp[32+e] + b_sp[e];
      }
      { // a-prep: wave w owns N-tiles w*2, w*2+1; loop over 4 M-tiles -> a_g
        u32x4 ph[2][2], pl[2][2];
        load_frags<2,2>(PWH, PWL, w*2, lane, ph, pl);
        #pragma unroll
        for (int mt = 0; mt < 4; ++mt) {
          f32x4 pacc[2];
          pacc[0] = (f32x4){0.f,0.f,0.f,0.f};
          pacc[1] = (f32x4){0.f,0.f,0.f,0.f};
          mfma_compute<2,2>(ph, pl, lane, &hl[(mt*16 + colq)*68], pacc);
          #pragma unroll
          for (int i = 0; i < 2; ++i) {
            int n = (w*2 + i)*16 + colq;
            float a3x = A3[n], a3y = A3[512 + n], a3s = A3[1024 + n], cst = Cst[n];
            #pragma unroll
            for (int r = 0; r < 4; ++r) {
              int p2 = mt*16 + kg*4 + r;
              float val = pacc[i][r] + pos_s[p2*2+0]*a3x + pos_s[p2*2+1]*a3y
                        + spd_s[p2]*a3s + cst;
              a_g[(size_t)(base + p2)*PPH + n] = f2h(val);
            }
          }
        }
      }
    }
    __syncthreads();   // a_g stores drained (vmcnt) before next t's DMA; spd/rel reuse
  }
}

// ---------- per-step (fallback): verified R2 ----------
__global__ __launch_bounds__(256) void k_step(
    int t,
    const float* __restrict__ h0, const float* __restrict__ pps,
    float* __restrict__ c, float* __restrict__ h_lstm,
    float* __restrict__ pos, float* __restrict__ x, const float* __restrict__ pool,
    const float* __restrict__ b_ih, const float* __restrict__ b_hh,
    const float* __restrict__ W_h2p, const float* __restrict__ b_h2p,
    const float* __restrict__ W_sp, const float* __restrict__ b_sp,
    const float* __restrict__ b_m1, const float* __restrict__ b_m2,
    const float* __restrict__ A3, const float* __restrict__ Cst,
    const u16* __restrict__ GWH, const u16* __restrict__ GWL,
    const u16* __restrict__ D1H, const u16* __restrict__ D1L,
    const u16* __restrict__ D2H, const u16* __restrict__ D2L,
    const u16* __restrict__ PWH, const u16* __restrict__ PWL,
    u16* __restrict__ a_bf, float* __restrict__ out)
{
  __shared__ float zin[16][100];
  __shared__ float o1[16][68];
  __shared__ float as_[16][100];
  __shared__ float hl[16][68];
  __shared__ float gl[16][260];
  __shared__ float rel_s[16][2], pos_s[16][2], spd_s[16];

  const int tid = threadIdx.x;
  const int p0 = blockIdx.x * 16;
  const int w = tid >> 6, lane = tid & 63, colq = lane & 15, kg = lane >> 4;
  const int tsp = (t + 1 < 12) ? t + 1 : 11;

  { int p = tid >> 4, e = tid & 15;
    as_[p][e] = x[(p0 + p) * E + e];
    as_[p][80 + e] = 0.f; }
  if (tid < 16) spd_s[tid] = pps[tsp * NPED + p0 + tid];
  if (t == 0) {
    #pragma unroll
    for (int q = 0; q < 4; ++q) {
      int idx = tid + 256*q; int p = idx >> 6, d = idx & 63;
      as_[p][16 + d] = h0[(p0 + p) * H + d];
    }
  } else {
    #pragma unroll
    for (int q = 0; q < 4; ++q) {
      int idx = tid + 256*q; int p = idx >> 6, d = idx & 63;
      zin[p][d] = h_lstm[(p0 + p) * H + d];
    }
    #pragma unroll
    for (int q = 0; q < 2; ++q) {
      int idx = tid + 256*q; int p = idx >> 5, d = idx & 31;
      zin[p][64 + d] = pool[(p0 + p) * BOT + d];
    }
  }
  __syncthreads();

  if (t > 0) {
    {
      f32x4 acc = {0.f, 0.f, 0.f, 0.f};
      mfma_block<1,3>(D1H, D1L, w, lane, &zin[colq][0], 0, &acc);
      int n = w*16 + colq;
      float bm = b_m1[n];
      #pragma unroll
      for (int r = 0; r < 4; ++r) o1[kg*4 + r][n] = fmaxf(acc[r] + bm, 0.f);
    }
    __syncthreads();
    {
      f32x4 acc = {0.f, 0.f, 0.f, 0.f};
      mfma_block<1,2>(D2H, D2L, w, lane, &o1[colq][0], 0, &acc);
      int n = w*16 + colq;
      float bm = b_m2[n];
      #pragma unroll
      for (int r = 0; r < 4; ++r) as_[kg*4 + r][16 + n] = fmaxf(acc[r] + bm, 0.f);
    }
    __syncthreads();
  }

  {
    f32x4 gacc[4];
    #pragma unroll
    for (int i = 0; i < 4; ++i) gacc[i] = (f32x4){0.f,0.f,0.f,0.f};
    mfma_block<2,3>(GWH, GWL, w*4,     lane, &as_[colq][0], 0, &gacc[0]);
    mfma_block<2,3>(GWH, GWL, w*4 + 2, lane, &as_[colq][0], 0, &gacc[2]);
    #pragma unroll
    for (int i = 0; i < 4; ++i) {
      int n = (w*4 + i)*16 + colq;
      float bb = b_ih[n] + b_hh[n];
      #pragma unroll
      for (int r = 0; r < 4; ++r) gl[kg*4 + r][n] = gacc[i][r] + bb;
    }
  }
  __syncthreads();

  #pragma unroll
  for (int q = 0; q < 4; ++q) {
    int idx = tid + 256*q; int p = idx >> 6, d = idx & 63; int n = p0 + p;
    float gi = gl[p][d], gf = gl[p][64 + d], gg = gl[p][128 + d], go = gl[p][192 + d];
    float cv = c[n*H + d];
    float cn = sigm(gf) * cv + sigm(gi) * tanhf_(gg);
    float hv = sigm(go) * tanhf_(cn);
    c[n*H + d] = cn;
    hl[p][d] = hv;
    h_lstm[n*H + d] = hv;
  }
  __syncthreads();

  {
    int p = tid >> 4, l = tid & 15;
    f32x4 hv = *(const f32x4*)(&hl[p][0] + l*4);
    float s0 = hv.x * W_h2p[(l*4+0)*2]   + hv.y * W_h2p[(l*4+1)*2]
             + hv.z * W_h2p[(l*4+2)*2]   + hv.w * W_h2p[(l*4+3)*2];
    float s1 = hv.x * W_h2p[(l*4+0)*2+1] + hv.y * W_h2p[(l*4+1)*2+1]
             + hv.z * W_h2p[(l*4+2)*2+1] + hv.w * W_h2p[(l*4+3)*2+1];
    #pragma unroll
    for (int m = 1; m < 16; m <<= 1) {
      s0 += __shfl_xor(s0, m, 64);
      s1 += __shfl_xor(s1, m, 64);
    }
    if (l == 0) {
      float r0 = s0 + b_h2p[0], r1 = s1 + b_h2p[1];
      int n = p0 + p;
      float px = pos[n*2] + r0, py = pos[n*2+1] + r1;
      pos[n*2] = px; pos[n*2+1] = py;
      rel_s[p][0] = r0; rel_s[p][1] = r1;
      pos_s[p][0] = px; pos_s[p][1] = py;
      out[(t*NPED + n)*2] = r0; out[(t*NPED + n)*2 + 1] = r1;
    }
  }
  __syncthreads();

  if (t < 11) {
    {
      int p = tid >> 4, e = tid & 15;
      float xv = rel_s[p][0] * W_sp[e] + rel_s[p][1] * W_sp[16+e]
               + spd_s[p] * W_sp[32+e] + b_sp[e];
      x[(p0 + p) * E + e] = xv;
    }
    {
      f32x4 pacc[8];
      #pragma unroll
      for (int i = 0; i < 8; ++i) pacc[i] = (f32x4){0.f,0.f,0.f,0.f};
      mfma_block<4,2>(PWH, PWL, w*8,     lane, &hl[colq][0], 0, &pacc[0]);
      mfma_block<4,2>(PWH, PWL, w*8 + 4, lane, &hl[colq][0], 0, &pacc[4]);
      #pragma unroll
      for (int i = 0; i < 8; ++i) {
        int n = (w*8 + i)*16 + colq;
        float a3x = A3[n], a3y = A3[512 + n], a3s = A3[1024 + n], cst = Cst[n];
        #pragma unroll
        for (int r = 0; r < 4; ++r) {
          int p2 = kg*4 + r;
          float val = pacc[i][r] + pos_s[p2][0]*a3x + pos_s[p2][1]*a3y
                    + spd_s[p2]*a3s + cst;
          a_bf[(size_t)(p0 + p2)*PPH + n] = f2h(val);
        }
      }
    }
  }
}

// ---------- pooling (fallback path, verified R2) ----------
__global__ __launch_bounds__(1024) void k_pool(
    const u16* __restrict__ a_bf, const float* __restrict__ pos,
    const float* __restrict__ A3, const u16* __restrict__ W2t,
    const float* __restrict__ b_pp2, float* __restrict__ pool)
{
  constexpr int LDA = 520;
  extern __shared__ char smem_raw[];
  u16* a_s  = (u16*)smem_raw;
  u16* w2_s = a_s + 64 * LDA;
  f16* v_s  = (f16*)(w2_s + 32 * LDA);
  float* red = (float*)(v_s + 16 * 512);

  const int tid = threadIdx.x;
  const int s = blockIdx.y;
  const int i0 = blockIdx.x * 16;

  for (int idx = tid; idx < 4096; idx += 1024) {
    int r = idx >> 6, c8 = (idx & 63) * 8;
    *(u32x4*)&a_s[r * LDA + c8] = *(const u32x4*)&a_bf[(s * 64 + r) * PPH + c8];
  }
  for (int idx = tid; idx < 2048; idx += 1024) {
    int r = idx >> 6, c8 = (idx & 63) * 8;
    *(u32x4*)&w2_s[r * LDA + c8] = *(const u32x4*)&W2t[r * PPH + c8];
  }
  for (int idx = tid; idx < 4096; idx += 1024) {
    int i = idx >> 8, k2 = (idx & 255) * 2;
    int n = s * 64 + i0 + i;
    float px = pos[n * 2], py = pos[n * 2 + 1];
    float v0 = px * A3[k2]     + py * A3[512 + k2];
    float v1 = px * A3[k2 + 1] + py * A3[512 + k2 + 1];
    f16x2 pk = { (f16)v0, (f16)v1 };
    *(f16x2*)&v_s[i * 512 + k2] = pk;
  }
  __syncthreads();

  const int lane = tid & 63, w = tid >> 6;
  const int jq = w & 3, g = w >> 2;
  const int col = lane & 15, kg = lane >> 4;
  const int aoff  = (jq * 16 + col) * LDA + kg * 8;
  const int w0off = col * LDA + kg * 8;
  const int w1off = (col + 16) * LDA + kg * 8;
  const float b20 = b_pp2[col];
  const float b21 = b_pp2[col + 16];
  const f32x4 vzero = {0.f, 0.f, 0.f, 0.f};

  f32x4 accA[4], accB[4];
  #pragma unroll
  for (int ii = 0; ii < 4; ++ii) { accA[ii] = vzero; accB[ii] = vzero; }

  for (int kk = 0; kk < 16; ++kk) {
    const int ke = kk * 32;
    f16x8 a8  = __builtin_bit_cast(f16x8, *(const u32x4*)&a_s[aoff + ke]);
    f16x8 bw0 = __builtin_bit_cast(f16x8, *(const u32x4*)&w2_s[w0off + ke]);
    f16x8 bw1 = __builtin_bit_cast(f16x8, *(const u32x4*)&w2_s[w1off + ke]);
    #pragma unroll
    for (int ii = 0; ii < 4; ++ii) {
      f16x8 v8 = *(const f16x8*)&v_s[(g * 4 + ii) * 512 + ke + kg * 8];
      f16x8 tq = relu8(a8 - v8);
      accA[ii] = __builtin_amdgcn_mfma_f32_16x16x32_f16(tq, bw0, accA[ii], 0, 0, 0);
      accB[ii] = __builtin_amdgcn_mfma_f32_16x16x32_f16(tq, bw1, accB[ii], 0, 0, 0);
    }
  }

  #pragma unroll
  for (int ii = 0; ii < 4; ++ii) {
    float m0 = 0.f, m1 = 0.f;
    #pragma unroll
    for (int r = 0; r < 4; ++r) {
      m0 = fmaxf(m0, accA[ii][r] + b20);
      m1 = fmaxf(m1, accB[ii][r] + b21);
    }
    m0 = fmaxf(m0, __shfl_xor(m0, 16, 64));
    m0 = fmaxf(m0, __shfl_xor(m0, 32, 64));
    m1 = fmaxf(m1, __shfl_xor(m1, 16, 64));
    m1 = fmaxf(m1, __shfl_xor(m1, 32, 64));
    if (kg == 0) {
      red[((w * 4 + ii) * 2 + 0) * 16 + col] = m0;
      red[((w * 4 + ii) * 2 + 1) * 16 + col] = m1;
    }
  }
  __syncthreads();

  if (tid < 512) {
    int gg = tid >> 7, ii = (tid >> 5) & 3, tile = (tid >> 4) & 1, cc = tid & 15;
    float m = red[(((gg * 4 + 0) * 4 + ii) * 2 + tile) * 16 + cc];
    #pragma unroll
    for (int q = 1; q < 4; ++q)
      m = fmaxf(m, red[(((gg * 4 + q) * 4 + ii) * 2 + tile) * 16 + cc]);
    int i = i0 + gg * 4 + ii;
    pool[(s * 64 + i) * 32 + tile * 16 + cc] = m;
  }
}

// ---------- host ----------
extern "C" void kernel_launch(void* const* d_in, const int* in_sizes, int n_in,
                              void* d_out, int out_size, void* d_ws, size_t ws_size,
                              hipStream_t stream)
{
  const float* last_pos     = (const float*)d_in[0];
  const float* last_pos_rel = (const float*)d_in[1];
  const float* h0    = (const float*)d_in[2];
  const float* c0    = (const float*)d_in[3];
  const float* pps   = (const float*)d_in[4];
  const float* W_sp  = (const float*)d_in[5];
  const float* b_sp  = (const float*)d_in[6];
  const float* W_ih  = (const float*)d_in[7];
  const float* b_ih  = (const float*)d_in[8];
  const float* W_hh  = (const float*)d_in[9];
  const float* b_hh  = (const float*)d_in[10];
  const float* W_h2p = (const float*)d_in[11];
  const float* b_h2p = (const float*)d_in[12];
  const float* W_pe  = (const float*)d_in[13];
  const float* b_pe  = (const float*)d_in[14];
  const float* W_pp1 = (const float*)d_in[15];
  const float* b_pp1 = (const float*)d_in[16];
  const float* W_pp2 = (const float*)d_in[17];
  const float* b_pp2 = (const float*)d_in[18];
  const float* W_m1  = (const float*)d_in[19];
  const float* b_m1  = (const float*)d_in[20];
  const float* W_m2  = (const float*)d_in[21];
  const float* b_m2  = (const float*)d_in[22];

  char* ws = (char*)d_ws;
  float* c_buf  = (float*)(ws + OFF_C);
  float* h_lstm = (float*)(ws + OFF_HL);
  float* pos    = (float*)(ws + OFF_POS);
  float* x_buf  = (float*)(ws + OFF_X);
  float* pool   = (float*)(ws + OFF_POOL);
  u16*   abuf0  = (u16*)(ws + OFF_ABF);
  float* A3     = (float*)(ws + OFF_A3);
  float* Cst    = (float*)(ws + OFF_CST);
  u16*   W2t    = (u16*)(ws + OFF_W2T);
  u16* GWH = (u16*)(ws + OFF_GWH); u16* GWL = (u16*)(ws + OFF_GWL);
  u16* D1H = (u16*)(ws + OFF_D1H); u16* D1L = (u16*)(ws + OFF_D1L);
  u16* D2H = (u16*)(ws + OFF_D2H); u16* D2L = (u16*)(ws + OFF_D2L);
  u16* PWH = (u16*)(ws + OFF_PWH); u16* PWL = (u16*)(ws + OFF_PWL);
  float* out    = (float*)d_out;

  static int pers_ok = -1;
  if (pers_ok < 0) {
    hipError_t e = hipFuncSetAttribute(reinterpret_cast<const void*>(k_pers),
                                       hipFuncAttributeMaxDynamicSharedMemorySize, PERS_SMEM);
    pers_ok = (e == hipSuccess) ? 1 : 0;
  }

  k_setup<<<512, 256, 0, stream>>>(last_pos, last_pos_rel, c0, pps, W_sp, b_sp,
                                   W_pe, b_pe, W_pp1, b_pp1, W_pp2,
                                   W_ih, W_hh, W_m1, W_m2,
                                   c_buf, pos, x_buf, A3, Cst, W2t,
                                   GWH, GWL, D1H, D1L, D2H, D2L, PWH, PWL);

  if (pers_ok && ws_size >= WS_NEED_PERS) {
    k_pers<<<64, 1024, PERS_SMEM, stream>>>(
        h0, c0, pps, last_pos, x_buf,
        b_ih, b_hh, W_h2p, b_h2p, W_sp, b_sp, b_m1, b_m2, A3, Cst,
        GWH, GWL, D1H, D1L, D2H, D2L, PWH, PWL,
        W2t, b_pp2, abuf0, out);
  } else {
    hipFuncSetAttribute(reinterpret_cast<const void*>(k_pool),
                        hipFuncAttributeMaxDynamicSharedMemorySize, POOL_SMEM);
    k_step<<<256, 256, 0, stream>>>(0, h0, pps, c_buf, h_lstm, pos, x_buf, pool,
                                    b_ih, b_hh, W_h2p, b_h2p, W_sp, b_sp,
                                    b_m1, b_m2, A3, Cst,
                                    GWH, GWL, D1H, D1L, D2H, D2L, PWH, PWL,
                                    abuf0, out);
    for (int t = 1; t < TSTEPS; ++t) {
      k_pool<<<dim3(4, 64), 1024, POOL_SMEM, stream>>>(abuf0, pos, A3, W2t, b_pp2, pool);
      k_step<<<256, 256, 0, stream>>>(t, h0, pps, c_buf, h_lstm, pos, x_buf, pool,
                                      b_ih, b_hh, W_h2p, b_h2p, W_sp, b_sp,
                                      b_m1, b_m2, A3, Cst,
                                      GWH, GWL, D1H, D1L, D2H, D2L, PWH, PWL,
                                      abuf0, out);
    }
  }
}

// Round 10
// 266.160 us; speedup vs baseline: 3.5844x; 3.5844x over previous
//
#include <hip/hip_runtime.h>

typedef unsigned int  u32;
typedef unsigned short u16;
typedef float  f32x4 __attribute__((ext_vector_type(4)));
typedef u32    u32x4 __attribute__((ext_vector_type(4)));
typedef __bf16 bf16x8 __attribute__((ext_vector_type(8)));
typedef _Float16 f16;
typedef _Float16 f16x8 __attribute__((ext_vector_type(8)));
typedef _Float16 f16x2 __attribute__((ext_vector_type(2)));

static constexpr int NPED = 4096;
static constexpr int H = 64, E = 16, BOT = 32, PPH = 512;
static constexpr int TSTEPS = 12;

// ---------- helpers ----------
__device__ __forceinline__ float bf2f(u16 u) {
  return __builtin_bit_cast(float, ((u32)u) << 16);
}
__device__ __forceinline__ u16 f2bf(float f) {  // RNE
  u32 u = __builtin_bit_cast(u32, f);
  u += 0x7fffu + ((u >> 16) & 1u);
  return (u16)(u >> 16);
}
__device__ __forceinline__ u16 f2h(float f) {   // f32 -> f16 bits (RNE)
  return __builtin_bit_cast(u16, (f16)f);
}
__device__ __forceinline__ float sigm(float x) { return 1.f / (1.f + __expf(-x)); }
__device__ __forceinline__ float tanhf_(float x) {
  float t = fabsf(x);
  float e = __expf(-2.f * t);
  float r = (1.f - e) / (1.f + e);
  return x < 0.f ? -r : r;
}
__device__ __forceinline__ f16x8 relu8(f16x8 t) {
  const f16x8 z = {(f16)0, (f16)0, (f16)0, (f16)0, (f16)0, (f16)0, (f16)0, (f16)0};
#if __has_builtin(__builtin_elementwise_max)
  return __builtin_elementwise_max(t, z);
#else
  #pragma unroll
  for (int q = 0; q < 8; ++q) t[q] = t[q] > (f16)0 ? t[q] : (f16)0;
  return t;
#endif
}

// async 16B global->LDS copy. Call with PER-LANE pointers; the HW uses the
// wave-uniform base (first lane) + lane*16 for the LDS side, which matches
// our layout exactly (row base 16B-aligned, lane offset = lane*16B).
__device__ __forceinline__ void gload_lds16(const u16* __restrict__ g, u16* l) {
#if __has_builtin(__builtin_amdgcn_global_load_lds)
  __builtin_amdgcn_global_load_lds(
      (const __attribute__((address_space(1))) void*)g,
      (__attribute__((address_space(3))) void*)l, 16, 0, 0);
#else
  *(u32x4*)l = *(const u32x4*)g;
#endif
}

// ---------- workspace layout (bytes) ----------
static constexpr size_t OFF_C    = 0;        // f32 [4096][64]
static constexpr size_t OFF_HL   = 1048576;  // f32 [4096][64]
static constexpr size_t OFF_POS  = 2097152;  // f32 [4096][2]
static constexpr size_t OFF_X    = 2129920;  // f32 [4096][16]
static constexpr size_t OFF_POOL = 2392064;  // f32 [4096][32]
static constexpr size_t OFF_ABF  = 2916352;  // f16 [4096][512]  (buffer 0)
static constexpr size_t OFF_A3   = 7110656;  // f32 [3][512]
static constexpr size_t OFF_CST  = 7116800;  // f32 [512]
static constexpr size_t OFF_W2T  = 7118848;  // f16 [32][512]
// packed B-fragment weights (lane-ordered, bf16 hi + bf16 lo residual)
static constexpr size_t OFF_GWH  = 7151616;  // gates  [16 t][3 ks][64 lane][8]
static constexpr size_t OFF_GWL  = 7200768;
static constexpr size_t OFF_D1H  = 7249920;  // dec1   [4][3][64][8]
static constexpr size_t OFF_D1L  = 7262208;
static constexpr size_t OFF_D2H  = 7274496;  // dec2   [4][2][64][8]
static constexpr size_t OFF_D2L  = 7282688;
static constexpr size_t OFF_PWH  = 7290880;  // a-prep [32][2][64][8]
static constexpr size_t OFF_PWL  = 7356416;
static constexpr size_t OFF_ABF2 = 7421952;  // f16 [4096][512]  (buffer 1)
static constexpr size_t ABF_BYTES = (size_t)NPED * PPH * 2;   // 4 MiB
static constexpr size_t WS_NEED_FUSED = OFF_ABF2 + ABF_BYTES; // ~11.1 MiB

// fallback pool smem: a_s(f16) + w2_s(f16) + v_s(f16) + red(f32)
static constexpr int POOL_SMEM = 64*520*2 + 32*520*2 + 16*512*2 + 16*4*2*16*4; // 124416
// fused smem: a_s + w2_s + v_s + red + spd/rel/pos
static constexpr int FUSED_SMEM = POOL_SMEM + 64 + 128 + 128;  // 124736

// ---------- setup: state init + folded constants + fragment packing ----------
__global__ void k_setup(const float* __restrict__ last_pos, const float* __restrict__ last_pos_rel,
                        const float* __restrict__ c0, const float* __restrict__ pps,
                        const float* __restrict__ W_sp, const float* __restrict__ b_sp,
                        const float* __restrict__ W_pe, const float* __restrict__ b_pe,
                        const float* __restrict__ W_pp1, const float* __restrict__ b_pp1,
                        const float* __restrict__ W_pp2,
                        const float* __restrict__ W_ih, const float* __restrict__ W_hh,
                        const float* __restrict__ W_m1, const float* __restrict__ W_m2,
                        float* __restrict__ c, float* __restrict__ pos, float* __restrict__ x,
                        float* __restrict__ A3, float* __restrict__ Cst, u16* __restrict__ W2t,
                        u16* GWH, u16* GWL, u16* D1H, u16* D1L,
                        u16* D2H, u16* D2L, u16* PWH, u16* PWL)
{
  const int stride = gridDim.x * blockDim.x;
  const int tid0 = blockIdx.x * blockDim.x + threadIdx.x;
  for (int i = tid0; i < NPED * H; i += stride) c[i] = c0[i];
  for (int i = tid0; i < NPED * 2; i += stride) pos[i] = last_pos[i];
  for (int i = tid0; i < NPED * E; i += stride) {
    int n = i >> 4, e = i & 15;
    x[i] = last_pos_rel[2*n] * W_sp[e] + last_pos_rel[2*n+1] * W_sp[16+e]
         + pps[n] * W_sp[32+e] + b_sp[e];
  }
  for (int i = tid0; i < 3 * PPH; i += stride) {   // A3 = W_pe @ W_pp1[64:80]
    int r = i >> 9, k = i & 511;
    float s = 0.f;
    for (int e = 0; e < 16; ++e) s += W_pe[r*16+e] * W_pp1[(64+e)*PPH + k];
    A3[i] = s;
  }
  for (int i = tid0; i < PPH; i += stride) {       // Cst = b_pe @ W_pp1[64:80] + b_pp1
    float s = b_pp1[i];
    for (int e = 0; e < 16; ++e) s += b_pe[e] * W_pp1[(64+e)*PPH + i];
    Cst[i] = s;
  }
  for (int i = tid0; i < 32 * PPH; i += stride) {  // W2t[n][k] = f16(W_pp2[k][n])
    int n = i >> 9, k = i & 511;
    W2t[i] = f2h(W_pp2[k*32 + n]);
  }
  // gates pack: [K=96 pad][N=256], A = [x(16)|h(64)|0(16)]
  for (int i = tid0; i < 256*96; i += stride) {
    int n = i / 96, k = i - n*96;
    float wv = (k < 16) ? W_ih[k*256+n] : ((k < 80) ? W_hh[(k-16)*256+n] : 0.f);
    u16 hi = f2bf(wv); u16 lo = f2bf(wv - bf2f(hi));
    int idx = (((n>>4)*3 + (k>>5))*64 + ((k>>3)&3)*16 + (n&15))*8 + (k&7);
    GWH[idx] = hi; GWL[idx] = lo;
  }
  // dec1 pack: W_m1 [96][64]
  for (int i = tid0; i < 64*96; i += stride) {
    int n = i / 96, k = i - n*96;
    float wv = W_m1[k*64 + n];
    u16 hi = f2bf(wv); u16 lo = f2bf(wv - bf2f(hi));
    int idx = (((n>>4)*3 + (k>>5))*64 + ((k>>3)&3)*16 + (n&15))*8 + (k&7);
    D1H[idx] = hi; D1L[idx] = lo;
  }
  // dec2 pack: W_m2 [64][64]
  for (int i = tid0; i < 64*64; i += stride) {
    int n = i >> 6, k = i & 63;
    float wv = W_m2[k*64 + n];
    u16 hi = f2bf(wv); u16 lo = f2bf(wv - bf2f(hi));
    int idx = (((n>>4)*2 + (k>>5))*64 + ((k>>3)&3)*16 + (n&15))*8 + (k&7);
    D2H[idx] = hi; D2L[idx] = lo;
  }
  // a-prep pack: W_pp1[:64] [64][512]
  for (int i = tid0; i < 512*64; i += stride) {
    int n = i >> 6, k = i & 63;
    float wv = W_pp1[k*PPH + n];
    u16 hi = f2bf(wv); u16 lo = f2bf(wv - bf2f(hi));
    int idx = (((n>>4)*2 + (k>>5))*64 + ((k>>3)&3)*16 + (n&15))*8 + (k&7);
    PWH[idx] = hi; PWL[idx] = lo;
  }
}

// ---------- split MFMA helpers: load fragments / compute (bf16x3 split GEMM) ----------
template<int NT, int NKS>
__device__ __forceinline__ void load_frags(const u16* __restrict__ WH, const u16* __restrict__ WL,
                                           int tile0, int lane,
                                           u32x4 (&bh)[NT][NKS], u32x4 (&bl)[NT][NKS])
{
  #pragma unroll
  for (int i = 0; i < NT; ++i)
    #pragma unroll
    for (int ks = 0; ks < NKS; ++ks) {
      int o = (((tile0 + i)*NKS + ks)*64 + lane)*8;
      bh[i][ks] = *(const u32x4*)(WH + o);
      bl[i][ks] = *(const u32x4*)(WL + o);
    }
}

template<int NT, int NKS>
__device__ __forceinline__ void mfma_compute(const u32x4 (&bh)[NT][NKS], const u32x4 (&bl)[NT][NKS],
                                             int lane, const float* arow, f32x4* acc)
{
  const int kg = lane >> 4;
  #pragma unroll
  for (int ks = 0; ks < NKS; ++ks) {
    f32x4 a0 = *(const f32x4*)(arow + ks*32 + kg*8);
    f32x4 a1 = *(const f32x4*)(arow + ks*32 + kg*8 + 4);
    float av[8] = {a0.x,a0.y,a0.z,a0.w,a1.x,a1.y,a1.z,a1.w};
    bf16x8 ah, al;
    #pragma unroll
    for (int j = 0; j < 8; ++j) {
      __bf16 hbits = (__bf16)av[j];
      ah[j] = hbits;
      al[j] = (__bf16)(av[j] - (float)hbits);
    }
    #pragma unroll
    for (int i = 0; i < NT; ++i) {
      bf16x8 BH = __builtin_bit_cast(bf16x8, bh[i][ks]);
      bf16x8 BL = __builtin_bit_cast(bf16x8, bl[i][ks]);
      acc[i] = __builtin_amdgcn_mfma_f32_16x16x32_bf16(ah, BH, acc[i], 0, 0, 0);
      acc[i] = __builtin_amdgcn_mfma_f32_16x16x32_bf16(ah, BL, acc[i], 0, 0, 0);
      acc[i] = __builtin_amdgcn_mfma_f32_16x16x32_bf16(al, BH, acc[i], 0, 0, 0);
    }
  }
}

template<int NT, int NKS>
__device__ __forceinline__ void mfma_block(
    const u16* __restrict__ WH, const u16* __restrict__ WL, int tile0, int lane,
    const float* arow, int acol0, f32x4* acc)
{
  u32x4 bh[NT][NKS], bl[NT][NKS];
  load_frags<NT,NKS>(WH, WL, tile0, lane, bh, bl);
  mfma_compute<NT,NKS>(bh, bl, lane, arow + acol0, acc);
}

// ---------- per-step (fallback): decoder(prev) + LSTM + h2p + x_new + a-prep ----------
__global__ __launch_bounds__(256) void k_step(
    int t,
    const float* __restrict__ h0, const float* __restrict__ pps,
    float* __restrict__ c, float* __restrict__ h_lstm,
    float* __restrict__ pos, float* __restrict__ x, const float* __restrict__ pool,
    const float* __restrict__ b_ih, const float* __restrict__ b_hh,
    const float* __restrict__ W_h2p, const float* __restrict__ b_h2p,
    const float* __restrict__ W_sp, const float* __restrict__ b_sp,
    const float* __restrict__ b_m1, const float* __restrict__ b_m2,
    const float* __restrict__ A3, const float* __restrict__ Cst,
    const u16* __restrict__ GWH, const u16* __restrict__ GWL,
    const u16* __restrict__ D1H, const u16* __restrict__ D1L,
    const u16* __restrict__ D2H, const u16* __restrict__ D2L,
    const u16* __restrict__ PWH, const u16* __restrict__ PWL,
    u16* __restrict__ a_bf, float* __restrict__ out)
{
  __shared__ float zin[16][100];
  __shared__ float o1[16][68];
  __shared__ float as_[16][100];
  __shared__ float hl[16][68];
  __shared__ float gl[16][260];
  __shared__ float rel_s[16][2], pos_s[16][2], spd_s[16];

  const int tid = threadIdx.x;
  const int p0 = blockIdx.x * 16;
  const int w = tid >> 6, lane = tid & 63, colq = lane & 15, kg = lane >> 4;
  const int tsp = (t + 1 < 12) ? t + 1 : 11;

  { int p = tid >> 4, e = tid & 15;
    as_[p][e] = x[(p0 + p) * E + e];
    as_[p][80 + e] = 0.f; }
  if (tid < 16) spd_s[tid] = pps[tsp * NPED + p0 + tid];
  if (t == 0) {
    #pragma unroll
    for (int q = 0; q < 4; ++q) {
      int idx = tid + 256*q; int p = idx >> 6, d = idx & 63;
      as_[p][16 + d] = h0[(p0 + p) * H + d];
    }
  } else {
    #pragma unroll
    for (int q = 0; q < 4; ++q) {
      int idx = tid + 256*q; int p = idx >> 6, d = idx & 63;
      zin[p][d] = h_lstm[(p0 + p) * H + d];
    }
    #pragma unroll
    for (int q = 0; q < 2; ++q) {
      int idx = tid + 256*q; int p = idx >> 5, d = idx & 31;
      zin[p][64 + d] = pool[(p0 + p) * BOT + d];
    }
  }
  __syncthreads();

  if (t > 0) {
    {
      f32x4 acc = {0.f, 0.f, 0.f, 0.f};
      mfma_block<1,3>(D1H, D1L, w, lane, &zin[colq][0], 0, &acc);
      int n = w*16 + colq;
      float bm = b_m1[n];
      #pragma unroll
      for (int r = 0; r < 4; ++r) o1[kg*4 + r][n] = fmaxf(acc[r] + bm, 0.f);
    }
    __syncthreads();
    {
      f32x4 acc = {0.f, 0.f, 0.f, 0.f};
      mfma_block<1,2>(D2H, D2L, w, lane, &o1[colq][0], 0, &acc);
      int n = w*16 + colq;
      float bm = b_m2[n];
      #pragma unroll
      for (int r = 0; r < 4; ++r) as_[kg*4 + r][16 + n] = fmaxf(acc[r] + bm, 0.f);
    }
    __syncthreads();
  }

  {
    f32x4 gacc[4];
    #pragma unroll
    for (int i = 0; i < 4; ++i) gacc[i] = (f32x4){0.f,0.f,0.f,0.f};
    mfma_block<2,3>(GWH, GWL, w*4,     lane, &as_[colq][0], 0, &gacc[0]);
    mfma_block<2,3>(GWH, GWL, w*4 + 2, lane, &as_[colq][0], 0, &gacc[2]);
    #pragma unroll
    for (int i = 0; i < 4; ++i) {
      int n = (w*4 + i)*16 + colq;
      float bb = b_ih[n] + b_hh[n];
      #pragma unroll
      for (int r = 0; r < 4; ++r) gl[kg*4 + r][n] = gacc[i][r] + bb;
    }
  }
  __syncthreads();

  #pragma unroll
  for (int q = 0; q < 4; ++q) {
    int idx = tid + 256*q; int p = idx >> 6, d = idx & 63; int n = p0 + p;
    float gi = gl[p][d], gf = gl[p][64 + d], gg = gl[p][128 + d], go = gl[p][192 + d];
    float cv = c[n*H + d];
    float cn = sigm(gf) * cv + sigm(gi) * tanhf_(gg);
    float hv = sigm(go) * tanhf_(cn);
    c[n*H + d] = cn;
    hl[p][d] = hv;
    h_lstm[n*H + d] = hv;
  }
  __syncthreads();

  {
    int p = tid >> 4, l = tid & 15;
    f32x4 hv = *(const f32x4*)(&hl[p][0] + l*4);
    float s0 = hv.x * W_h2p[(l*4+0)*2]   + hv.y * W_h2p[(l*4+1)*2]
             + hv.z * W_h2p[(l*4+2)*2]   + hv.w * W_h2p[(l*4+3)*2];
    float s1 = hv.x * W_h2p[(l*4+0)*2+1] + hv.y * W_h2p[(l*4+1)*2+1]
             + hv.z * W_h2p[(l*4+2)*2+1] + hv.w * W_h2p[(l*4+3)*2+1];
    #pragma unroll
    for (int m = 1; m < 16; m <<= 1) {
      s0 += __shfl_xor(s0, m, 64);
      s1 += __shfl_xor(s1, m, 64);
    }
    if (l == 0) {
      float r0 = s0 + b_h2p[0], r1 = s1 + b_h2p[1];
      int n = p0 + p;
      float px = pos[n*2] + r0, py = pos[n*2+1] + r1;
      pos[n*2] = px; pos[n*2+1] = py;
      rel_s[p][0] = r0; rel_s[p][1] = r1;
      pos_s[p][0] = px; pos_s[p][1] = py;
      out[(t*NPED + n)*2] = r0; out[(t*NPED + n)*2 + 1] = r1;
    }
  }
  __syncthreads();

  if (t < 11) {
    {
      int p = tid >> 4, e = tid & 15;
      float xv = rel_s[p][0] * W_sp[e] + rel_s[p][1] * W_sp[16+e]
               + spd_s[p] * W_sp[32+e] + b_sp[e];
      x[(p0 + p) * E + e] = xv;
    }
    {
      f32x4 pacc[8];
      #pragma unroll
      for (int i = 0; i < 8; ++i) pacc[i] = (f32x4){0.f,0.f,0.f,0.f};
      mfma_block<4,2>(PWH, PWL, w*8,     lane, &hl[colq][0], 0, &pacc[0]);
      mfma_block<4,2>(PWH, PWL, w*8 + 4, lane, &hl[colq][0], 0, &pacc[4]);
      #pragma unroll
      for (int i = 0; i < 8; ++i) {
        int n = (w*8 + i)*16 + colq;
        float a3x = A3[n], a3y = A3[512 + n], a3s = A3[1024 + n], cst = Cst[n];
        #pragma unroll
        for (int r = 0; r < 4; ++r) {
          int p2 = kg*4 + r;
          float val = pacc[i][r] + pos_s[p2][0]*a3x + pos_s[p2][1]*a3y
                    + spd_s[p2]*a3s + cst;
          a_bf[(size_t)(p0 + p2)*PPH + n] = f2h(val);
        }
      }
    }
  }
}

// ---------- pooling (fallback path, verified R2) ----------
__global__ __launch_bounds__(1024) void k_pool(
    const u16* __restrict__ a_bf, const float* __restrict__ pos,
    const float* __restrict__ A3, const u16* __restrict__ W2t,
    const float* __restrict__ b_pp2, float* __restrict__ pool)
{
  constexpr int LDA = 520;
  extern __shared__ char smem_raw[];
  u16* a_s  = (u16*)smem_raw;
  u16* w2_s = a_s + 64 * LDA;
  f16* v_s  = (f16*)(w2_s + 32 * LDA);
  float* red = (float*)(v_s + 16 * 512);

  const int tid = threadIdx.x;
  const int s = blockIdx.y;
  const int i0 = blockIdx.x * 16;

  for (int idx = tid; idx < 4096; idx += 1024) {
    int r = idx >> 6, c8 = (idx & 63) * 8;
    *(u32x4*)&a_s[r * LDA + c8] = *(const u32x4*)&a_bf[(s * 64 + r) * PPH + c8];
  }
  for (int idx = tid; idx < 2048; idx += 1024) {
    int r = idx >> 6, c8 = (idx & 63) * 8;
    *(u32x4*)&w2_s[r * LDA + c8] = *(const u32x4*)&W2t[r * PPH + c8];
  }
  for (int idx = tid; idx < 4096; idx += 1024) {
    int i = idx >> 8, k2 = (idx & 255) * 2;
    int n = s * 64 + i0 + i;
    float px = pos[n * 2], py = pos[n * 2 + 1];
    float v0 = px * A3[k2]     + py * A3[512 + k2];
    float v1 = px * A3[k2 + 1] + py * A3[512 + k2 + 1];
    f16x2 pk = { (f16)v0, (f16)v1 };
    *(f16x2*)&v_s[i * 512 + k2] = pk;
  }
  __syncthreads();

  const int lane = tid & 63, w = tid >> 6;
  const int jq = w & 3, g = w >> 2;
  const int col = lane & 15, kg = lane >> 4;
  const int aoff  = (jq * 16 + col) * LDA + kg * 8;
  const int w0off = col * LDA + kg * 8;
  const int w1off = (col + 16) * LDA + kg * 8;
  const float b20 = b_pp2[col];
  const float b21 = b_pp2[col + 16];
  const f32x4 vzero = {0.f, 0.f, 0.f, 0.f};

  f32x4 accA[4], accB[4];
  #pragma unroll
  for (int ii = 0; ii < 4; ++ii) { accA[ii] = vzero; accB[ii] = vzero; }

  for (int kk = 0; kk < 16; ++kk) {
    const int ke = kk * 32;
    f16x8 a8  = __builtin_bit_cast(f16x8, *(const u32x4*)&a_s[aoff + ke]);
    f16x8 bw0 = __builtin_bit_cast(f16x8, *(const u32x4*)&w2_s[w0off + ke]);
    f16x8 bw1 = __builtin_bit_cast(f16x8, *(const u32x4*)&w2_s[w1off + ke]);
    #pragma unroll
    for (int ii = 0; ii < 4; ++ii) {
      f16x8 v8 = *(const f16x8*)&v_s[(g * 4 + ii) * 512 + ke + kg * 8];
      f16x8 tq = relu8(a8 - v8);
      accA[ii] = __builtin_amdgcn_mfma_f32_16x16x32_f16(tq, bw0, accA[ii], 0, 0, 0);
      accB[ii] = __builtin_amdgcn_mfma_f32_16x16x32_f16(tq, bw1, accB[ii], 0, 0, 0);
    }
  }

  #pragma unroll
  for (int ii = 0; ii < 4; ++ii) {
    float m0 = 0.f, m1 = 0.f;
    #pragma unroll
    for (int r = 0; r < 4; ++r) {
      m0 = fmaxf(m0, accA[ii][r] + b20);
      m1 = fmaxf(m1, accB[ii][r] + b21);
    }
    m0 = fmaxf(m0, __shfl_xor(m0, 16, 64));
    m0 = fmaxf(m0, __shfl_xor(m0, 32, 64));
    m1 = fmaxf(m1, __shfl_xor(m1, 16, 64));
    m1 = fmaxf(m1, __shfl_xor(m1, 32, 64));
    if (kg == 0) {
      red[((w * 4 + ii) * 2 + 0) * 16 + col] = m0;
      red[((w * 4 + ii) * 2 + 1) * 16 + col] = m1;
    }
  }
  __syncthreads();

  if (tid < 512) {
    int gg = tid >> 7, ii = (tid >> 5) & 3, tile = (tid >> 4) & 1, cc = tid & 15;
    float m = red[(((gg * 4 + 0) * 4 + ii) * 2 + tile) * 16 + cc];
    #pragma unroll
    for (int q = 1; q < 4; ++q)
      m = fmaxf(m, red[(((gg * 4 + q) * 4 + ii) * 2 + tile) * 16 + cc]);
    int i = i0 + gg * 4 + ii;
    pool[(s * 64 + i) * 32 + tile * 16 + cc] = m;
  }
}

// ---------- fused: pool(t-1) + step(t), 1024 threads, 16 waves ----------
// R6 structure + (a) global_load_lds DMA staging for a_s/w2_s (latency
// overlaps v_s compute; identical bytes), (b) t==0 handled here too (skip
// pool phase; h from h0) so the whole schedule is k_setup + 12 fused.
__global__ __launch_bounds__(1024) void k_fused(
    int t,
    const float* __restrict__ h0, const float* __restrict__ pps,
    float* __restrict__ c, float* __restrict__ h_lstm,
    float* __restrict__ pos, float* __restrict__ x,
    const float* __restrict__ b_ih, const float* __restrict__ b_hh,
    const float* __restrict__ W_h2p, const float* __restrict__ b_h2p,
    const float* __restrict__ W_sp, const float* __restrict__ b_sp,
    const float* __restrict__ b_m1, const float* __restrict__ b_m2,
    const float* __restrict__ A3, const float* __restrict__ Cst,
    const u16* __restrict__ GWH, const u16* __restrict__ GWL,
    const u16* __restrict__ D1H, const u16* __restrict__ D1L,
    const u16* __restrict__ D2H, const u16* __restrict__ D2L,
    const u16* __restrict__ PWH, const u16* __restrict__ PWL,
    const u16* __restrict__ W2t, const float* __restrict__ b_pp2,
    const u16* __restrict__ a_read, u16* __restrict__ a_write,
    float* __restrict__ out)
{
  constexpr int LDA = 520;
  extern __shared__ char smem_raw[];
  u16*   a_s    = (u16*)smem_raw;                 // [64][LDA] f16
  u16*   w2_s   = a_s + 64 * LDA;                 // [32][LDA] f16
  f16*   v_s    = (f16*)(w2_s + 32 * LDA);        // [16][512] f16
  float* red    = (float*)(v_s + 16 * 512);       // [16][4][2][16] f32
  float* spd_s  = red + 16*4*2*16;                // [16]
  float* rel_s  = spd_s + 16;                     // [16][2]
  float* pos_s  = rel_s + 32;                     // [16][2]
  // step-phase arrays alias the a_s/w2_s region (pool reads finish first)
  float* zin = (float*)smem_raw;                  // [16][100]
  float* o1  = zin + 16*100;                      // [16][68]
  float* as_ = o1  + 16*68;                       // [16][100]
  float* hl  = as_ + 16*100;                      // [16][68]
  float* gl  = hl  + 16*68;                       // [16][260]  (38144 B < 66560 B)

  const int tid = threadIdx.x;
  const int s = blockIdx.y;
  const int i0 = blockIdx.x * 16;
  const int p0 = s * 64 + i0;
  const int lane = tid & 63, w = tid >> 6;
  const int colq = lane & 15, kg = lane >> 4;
  const int sd = tid & 63;                        // lane == d for LSTM mapping
  const int tsp = (t + 1 < 12) ? t + 1 : 11;

  // ---- prefetch step inputs into registers (latency hidden under pool) ----
  const float* hsrc = (t == 0) ? h0 : h_lstm;
  float hreg = hsrc[(p0 + w) * H + sd];
  float creg = c[(p0 + w) * H + sd];
  float whp0 = W_h2p[2 * sd], whp1 = W_h2p[2 * sd + 1];
  float xreg = 0.f;
  if (tid < 256) xreg = x[(p0 + (tid >> 4)) * E + (tid & 15)];
  if (tid < 16) spd_s[tid] = pps[tsp * NPED + p0 + tid];

  // fragment registers live across the pool phase boundary
  u32x4 gh[1][3], glo[1][3];
  u32x4 d1h_[1][3], d1l_[1][3], d2h_[1][2], d2l_[1][2];

  if (t > 0) {
    // ---- pool staging: a_s / w2_s via async DMA; v_s computed meanwhile ----
    #pragma unroll
    for (int q = 0; q < 4; ++q) {
      int r = w + 16 * q;                        // wave-uniform row
      gload_lds16(&a_read[(size_t)(s * 64 + r) * PPH + lane * 8],
                  &a_s[r * LDA + lane * 8]);
    }
    #pragma unroll
    for (int q = 0; q < 2; ++q) {
      int r = w + 16 * q;
      gload_lds16(&W2t[(size_t)r * PPH + lane * 8],
                  &w2_s[r * LDA + lane * 8]);
    }
    for (int idx = tid; idx < 4096; idx += 1024) {
      int i = idx >> 8, k2 = (idx & 255) * 2;
      int n = s * 64 + i0 + i;
      float px = pos[n * 2], py = pos[n * 2 + 1];
      float v0 = px * A3[k2]     + py * A3[512 + k2];
      float v1 = px * A3[k2 + 1] + py * A3[512 + k2 + 1];
      f16x2 pk = { (f16)v0, (f16)v1 };
      *(f16x2*)&v_s[i * 512 + k2] = pk;
    }
    __syncthreads();   // drains vmcnt (DMA) + lgkm

    // ---- pool main loop (verified datapath) ----
    {
      const int jq = w & 3, g = w >> 2;
      const int aoff  = (jq * 16 + colq) * LDA + kg * 8;
      const int w0off = colq * LDA + kg * 8;
      const int w1off = (colq + 16) * LDA + kg * 8;
      const float b20 = b_pp2[colq];
      const float b21 = b_pp2[colq + 16];
      const f32x4 vzero = {0.f, 0.f, 0.f, 0.f};

      f32x4 accA[4], accB[4];
      #pragma unroll
      for (int ii = 0; ii < 4; ++ii) { accA[ii] = vzero; accB[ii] = vzero; }

      for (int kk = 0; kk < 16; ++kk) {
        const int ke = kk * 32;
        f16x8 a8  = __builtin_bit_cast(f16x8, *(const u32x4*)&a_s[aoff + ke]);
        f16x8 bw0 = __builtin_bit_cast(f16x8, *(const u32x4*)&w2_s[w0off + ke]);
        f16x8 bw1 = __builtin_bit_cast(f16x8, *(const u32x4*)&w2_s[w1off + ke]);
        #pragma unroll
        for (int ii = 0; ii < 4; ++ii) {
          f16x8 v8 = *(const f16x8*)&v_s[(g * 4 + ii) * 512 + ke + kg * 8];
          f16x8 tq = relu8(a8 - v8);
          accA[ii] = __builtin_amdgcn_mfma_f32_16x16x32_f16(tq, bw0, accA[ii], 0, 0, 0);
          accB[ii] = __builtin_amdgcn_mfma_f32_16x16x32_f16(tq, bw1, accB[ii], 0, 0, 0);
        }
      }

      #pragma unroll
      for (int ii = 0; ii < 4; ++ii) {
        float m0 = 0.f, m1 = 0.f;
        #pragma unroll
        for (int r = 0; r < 4; ++r) {
          m0 = fmaxf(m0, accA[ii][r] + b20);
          m1 = fmaxf(m1, accB[ii][r] + b21);
        }
        m0 = fmaxf(m0, __shfl_xor(m0, 16, 64));
        m0 = fmaxf(m0, __shfl_xor(m0, 32, 64));
        m1 = fmaxf(m1, __shfl_xor(m1, 16, 64));
        m1 = fmaxf(m1, __shfl_xor(m1, 32, 64));
        if (kg == 0) {
          red[((w * 4 + ii) * 2 + 0) * 16 + colq] = m0;
          red[((w * 4 + ii) * 2 + 1) * 16 + colq] = m1;
        }
      }
    }
    // hoist weight fragments: L2 latency overlaps the barrier
    load_frags<1,3>(GWH, GWL, w, lane, gh, glo);
    if (w < 4) {
      load_frags<1,3>(D1H, D1L, w, lane, d1h_, d1l_);
      load_frags<1,2>(D2H, D2L, w, lane, d2h_, d2l_);
    }
    __syncthreads();

    // ---- merged interval: j-quarter reduction -> zin pool cols; stage h/x ----
    zin[w * 100 + sd] = hreg;
    if (tid < 512) {
      int gg = tid >> 7, ii = (tid >> 5) & 3, tile = (tid >> 4) & 1, cc = tid & 15;
      float m = red[(((gg * 4 + 0) * 4 + ii) * 2 + tile) * 16 + cc];
      #pragma unroll
      for (int q = 1; q < 4; ++q)
        m = fmaxf(m, red[(((gg * 4 + q) * 4 + ii) * 2 + tile) * 16 + cc]);
      zin[(gg * 4 + ii) * 100 + 64 + tile * 16 + cc] = m;
    }
    if (tid < 256) { int p = tid >> 4, e = tid & 15;
                     as_[p * 100 + e] = xreg; as_[p * 100 + 80 + e] = 0.f; }
    __syncthreads();

    // ---- dec1: 4 N-tiles on waves 0-3 ----
    if (w < 4) {
      f32x4 acc = {0.f, 0.f, 0.f, 0.f};
      mfma_compute<1,3>(d1h_, d1l_, lane, &zin[colq * 100], &acc);
      int n = w * 16 + colq;
      float bm = b_m1[n];
      #pragma unroll
      for (int r = 0; r < 4; ++r) o1[(kg * 4 + r) * 68 + n] = fmaxf(acc[r] + bm, 0.f);
    }
    __syncthreads();

    // ---- dec2 ----
    if (w < 4) {
      f32x4 acc = {0.f, 0.f, 0.f, 0.f};
      mfma_compute<1,2>(d2h_, d2l_, lane, &o1[colq * 68], &acc);
      int n = w * 16 + colq;
      float bm = b_m2[n];
      #pragma unroll
      for (int r = 0; r < 4; ++r) as_[(kg * 4 + r) * 100 + 16 + n] = fmaxf(acc[r] + bm, 0.f);
    }
    __syncthreads();
  } else {
    // ---- t == 0: no pool, no decoder; h comes straight from h0 ----
    load_frags<1,3>(GWH, GWL, w, lane, gh, glo);
    as_[w * 100 + 16 + sd] = hreg;
    if (tid < 256) { int p = tid >> 4, e = tid & 15;
                     as_[p * 100 + e] = xreg; as_[p * 100 + 80 + e] = 0.f; }
    __syncthreads();
  }

  // ---- gates: 16 N-tiles, one per wave ----
  {
    f32x4 acc = {0.f, 0.f, 0.f, 0.f};
    mfma_compute<1,3>(gh, glo, lane, &as_[colq * 100], &acc);
    int n = w * 16 + colq;
    float bb = b_ih[n] + b_hh[n];
    #pragma unroll
    for (int r = 0; r < 4; ++r) gl[(kg * 4 + r) * 260 + n] = acc[r] + bb;
  }
  // hoist a-prep fragments (overlap LSTM phase)
  u32x4 ph[2][2], pl[2][2];
  if (t < 11) load_frags<2,2>(PWH, PWL, w * 2, lane, ph, pl);
  __syncthreads();

  // ---- LSTM elementwise + fused h2p (wave w owns ped w; lanes = d) ----
  {
    int n = p0 + w;
    float gi = gl[w*260 + sd], gf = gl[w*260 + 64 + sd],
          gg = gl[w*260 + 128 + sd], go = gl[w*260 + 192 + sd];
    float cn = sigm(gf) * creg + sigm(gi) * tanhf_(gg);
    float hv = sigm(go) * tanhf_(cn);
    c[n*H + sd] = cn;
    hl[w*68 + sd] = hv;
    h_lstm[n*H + sd] = hv;
    // h2p: intra-wave dot products, 64-lane shfl-xor tree
    float s0 = hv * whp0, s1 = hv * whp1;
    #pragma unroll
    for (int m = 1; m < 64; m <<= 1) {
      s0 += __shfl_xor(s0, m, 64);
      s1 += __shfl_xor(s1, m, 64);
    }
    if (sd == 0) {
      float r0 = s0 + b_h2p[0], r1 = s1 + b_h2p[1];
      float px = pos[n*2] + r0, py = pos[n*2+1] + r1;
      pos[n*2] = px; pos[n*2+1] = py;
      rel_s[w*2+0] = r0; rel_s[w*2+1] = r1;
      pos_s[w*2+0] = px; pos_s[w*2+1] = py;
      out[(t*NPED + n)*2] = r0; out[(t*NPED + n)*2 + 1] = r1;
    }
  }
  __syncthreads();

  if (t < 11) {
    if (tid < 256) { // x_new
      int p = tid >> 4, e = tid & 15;
      float xv = rel_s[p*2+0] * W_sp[e] + rel_s[p*2+1] * W_sp[16+e]
               + spd_s[p] * W_sp[32+e] + b_sp[e];
      x[(p0 + p) * E + e] = xv;
    }
    { // a-prep: 32 N-tiles, 2 per wave -> a_write (next launch's pool input)
      f32x4 pacc[2];
      pacc[0] = (f32x4){0.f,0.f,0.f,0.f};
      pacc[1] = (f32x4){0.f,0.f,0.f,0.f};
      mfma_compute<2,2>(ph, pl, lane, &hl[colq * 68], pacc);
      #pragma unroll
      for (int i = 0; i < 2; ++i) {
        int n = (w * 2 + i) * 16 + colq;
        float a3x = A3[n], a3y = A3[512 + n], a3s = A3[1024 + n], cst = Cst[n];
        #pragma unroll
        for (int r = 0; r < 4; ++r) {
          int p2 = kg * 4 + r;
          float val = pacc[i][r] + pos_s[p2*2+0]*a3x + pos_s[p2*2+1]*a3y
                    + spd_s[p2]*a3s + cst;
          a_write[(size_t)(p0 + p2) * PPH + n] = f2h(val);
        }
      }
    }
  }
}

// ---------- host ----------
extern "C" void kernel_launch(void* const* d_in, const int* in_sizes, int n_in,
                              void* d_out, int out_size, void* d_ws, size_t ws_size,
                              hipStream_t stream)
{
  const float* last_pos     = (const float*)d_in[0];
  const float* last_pos_rel = (const float*)d_in[1];
  const float* h0    = (const float*)d_in[2];
  const float* c0    = (const float*)d_in[3];
  const float* pps   = (const float*)d_in[4];
  const float* W_sp  = (const float*)d_in[5];
  const float* b_sp  = (const float*)d_in[6];
  const float* W_ih  = (const float*)d_in[7];
  const float* b_ih  = (const float*)d_in[8];
  const float* W_hh  = (const float*)d_in[9];
  const float* b_hh  = (const float*)d_in[10];
  const float* W_h2p = (const float*)d_in[11];
  const float* b_h2p = (const float*)d_in[12];
  const float* W_pe  = (const float*)d_in[13];
  const float* b_pe  = (const float*)d_in[14];
  const float* W_pp1 = (const float*)d_in[15];
  const float* b_pp1 = (const float*)d_in[16];
  const float* W_pp2 = (const float*)d_in[17];
  const float* b_pp2 = (const float*)d_in[18];
  const float* W_m1  = (const float*)d_in[19];
  const float* b_m1  = (const float*)d_in[20];
  const float* W_m2  = (const float*)d_in[21];
  const float* b_m2  = (const float*)d_in[22];

  char* ws = (char*)d_ws;
  float* c_buf  = (float*)(ws + OFF_C);
  float* h_lstm = (float*)(ws + OFF_HL);
  float* pos    = (float*)(ws + OFF_POS);
  float* x_buf  = (float*)(ws + OFF_X);
  float* pool   = (float*)(ws + OFF_POOL);
  u16*   abuf0  = (u16*)(ws + OFF_ABF);
  float* A3     = (float*)(ws + OFF_A3);
  float* Cst    = (float*)(ws + OFF_CST);
  u16*   W2t    = (u16*)(ws + OFF_W2T);
  u16* GWH = (u16*)(ws + OFF_GWH); u16* GWL = (u16*)(ws + OFF_GWL);
  u16* D1H = (u16*)(ws + OFF_D1H); u16* D1L = (u16*)(ws + OFF_D1L);
  u16* D2H = (u16*)(ws + OFF_D2H); u16* D2L = (u16*)(ws + OFF_D2L);
  u16* PWH = (u16*)(ws + OFF_PWH); u16* PWL = (u16*)(ws + OFF_PWL);
  u16*   abuf1  = (u16*)(ws + OFF_ABF2);
  float* out    = (float*)d_out;

  const bool fused_ok = (ws_size >= WS_NEED_FUSED);

  hipFuncSetAttribute(reinterpret_cast<const void*>(k_pool),
                      hipFuncAttributeMaxDynamicSharedMemorySize, POOL_SMEM);
  hipFuncSetAttribute(reinterpret_cast<const void*>(k_fused),
                      hipFuncAttributeMaxDynamicSharedMemorySize, FUSED_SMEM);

  k_setup<<<512, 256, 0, stream>>>(last_pos, last_pos_rel, c0, pps, W_sp, b_sp,
                                   W_pe, b_pe, W_pp1, b_pp1, W_pp2,
                                   W_ih, W_hh, W_m1, W_m2,
                                   c_buf, pos, x_buf, A3, Cst, W2t,
                                   GWH, GWL, D1H, D1L, D2H, D2L, PWH, PWL);

  if (fused_ok) {
    for (int t = 0; t < TSTEPS; ++t) {
      const u16* ar = (t > 0 && ((t - 1) & 1)) ? abuf1 : abuf0;   // unused at t=0
      u16*       aw = (t & 1) ? abuf1 : abuf0;
      k_fused<<<dim3(4, 64), 1024, FUSED_SMEM, stream>>>(
          t, h0, pps, c_buf, h_lstm, pos, x_buf,
          b_ih, b_hh, W_h2p, b_h2p, W_sp, b_sp, b_m1, b_m2, A3, Cst,
          GWH, GWL, D1H, D1L, D2H, D2L, PWH, PWL,
          W2t, b_pp2, ar, aw, out);
    }
  } else {
    k_step<<<256, 256, 0, stream>>>(0, h0, pps, c_buf, h_lstm, pos, x_buf, pool,
                                    b_ih, b_hh, W_h2p, b_h2p, W_sp, b_sp,
                                    b_m1, b_m2, A3, Cst,
                                    GWH, GWL, D1H, D1L, D2H, D2L, PWH, PWL,
                                    abuf0, out);
    for (int t = 1; t < TSTEPS; ++t) {
      k_pool<<<dim3(4, 64), 1024, POOL_SMEM, stream>>>(abuf0, pos, A3, W2t, b_pp2, pool);
      k_step<<<256, 256, 0, stream>>>(t, h0, pps, c_buf, h_lstm, pos, x_buf, pool,
                                      b_ih, b_hh, W_h2p, b_h2p, W_sp, b_sp,
                                      b_m1, b_m2, A3, Cst,
                                      GWH, GWL, D1H, D1L, D2H, D2L, PWH, PWL,
                                      abuf0, out);
    }
  }
}